// Round 1
// baseline (983.956 us; speedup 1.0000x reference)
//
#include <hip/hip_runtime.h>
#include <math.h>

#define NB_NODES 100000
#define NB_EDGES 1600000
#define NB_GRAPHS 1000
constexpr float GN_EPS = 1e-5f;

// ---------------- histogram / degree ----------------
__global__ void hist_batch_k(const int* __restrict__ batch, int* __restrict__ counts) {
    int i = blockIdx.x * 256 + threadIdx.x;
    if (i < NB_NODES) atomicAdd(&counts[batch[i]], 1);
}

__global__ void hist_deg_k(const int* __restrict__ dst, int* __restrict__ deg_in) {
    int e = blockIdx.x * 256 + threadIdx.x;
    if (e < NB_EDGES) atomicAdd(&deg_in[dst[e]], 1);
}

__global__ void node_deg_k(const int* __restrict__ deg_in, float* __restrict__ dinv,
                           float* __restrict__ selfw) {
    int i = blockIdx.x * 256 + threadIdx.x;
    if (i < NB_NODES) {
        float d = (float)(deg_in[i] + 1);
        dinv[i]  = rsqrtf(d);
        selfw[i] = 1.0f / d;
    }
}

// ---------------- scans ----------------
// graph-start offsets: exclusive scan of counts[G], single block of 1024
__global__ void scan_g_k(const int* __restrict__ counts, int* __restrict__ gstart) {
    __shared__ int s[1024];
    int tid = threadIdx.x;
    int own = (tid < NB_GRAPHS) ? counts[tid] : 0;
    s[tid] = own;
    __syncthreads();
    for (int off = 1; off < 1024; off <<= 1) {
        int t = (tid >= off) ? s[tid - off] : 0;
        __syncthreads();
        s[tid] += t;
        __syncthreads();
    }
    if (tid < NB_GRAPHS) gstart[tid] = s[tid] - own;
    if (tid == 0) gstart[NB_GRAPHS] = NB_NODES;
}

// rowptr = exclusive scan of deg_in[N]; 98 blocks x 1024 elems
__global__ void scanA_k(const int* __restrict__ deg_in, int* __restrict__ bsums) {
    __shared__ int red[256];
    int tid = threadIdx.x;
    int base = blockIdx.x * 1024 + tid * 4;
    int s = 0;
#pragma unroll
    for (int i = 0; i < 4; i++) {
        int idx = base + i;
        s += (idx < NB_NODES) ? deg_in[idx] : 0;
    }
    red[tid] = s;
    __syncthreads();
    for (int st = 128; st > 0; st >>= 1) {
        if (tid < st) red[tid] += red[tid + st];
        __syncthreads();
    }
    if (tid == 0) bsums[blockIdx.x] = red[0];
}

__global__ void scanB_k(const int* __restrict__ bsums, int* __restrict__ boffs) {
    __shared__ int s[128];
    int tid = threadIdx.x;
    int own = (tid < 98) ? bsums[tid] : 0;
    s[tid] = own;
    __syncthreads();
    for (int off = 1; off < 128; off <<= 1) {
        int t = (tid >= off) ? s[tid - off] : 0;
        __syncthreads();
        s[tid] += t;
        __syncthreads();
    }
    if (tid < 98) boffs[tid] = s[tid] - own;
}

__global__ void scanC_k(const int* __restrict__ deg_in, const int* __restrict__ boffs,
                        int* __restrict__ rowptr) {
    __shared__ int s[256];
    int tid = threadIdx.x;
    int base = blockIdx.x * 1024 + tid * 4;
    int v[4];
    int tsum = 0;
#pragma unroll
    for (int i = 0; i < 4; i++) {
        v[i] = (base + i < NB_NODES) ? deg_in[base + i] : 0;
        tsum += v[i];
    }
    s[tid] = tsum;
    __syncthreads();
    for (int off = 1; off < 256; off <<= 1) {
        int t = (tid >= off) ? s[tid - off] : 0;
        __syncthreads();
        s[tid] += t;
        __syncthreads();
    }
    int run = boffs[blockIdx.x] + s[tid] - tsum;
#pragma unroll
    for (int i = 0; i < 4; i++) {
        if (base + i < NB_NODES) rowptr[base + i] = run;
        run += v[i];
    }
    if (blockIdx.x == 0 && tid == 0) rowptr[NB_NODES] = NB_EDGES;
}

__global__ void csr_fill_k(const int* __restrict__ ei, const int* __restrict__ rowptr,
                           int* __restrict__ cursor, int* __restrict__ csr_src) {
    int e = blockIdx.x * 256 + threadIdx.x;
    if (e < NB_EDGES) {
        int s = ei[e];
        int d = ei[NB_EDGES + e];
        int pos = atomicAdd(&cursor[d], 1);
        csr_src[rowptr[d] + pos] = s;
    }
}

// ---------------- GraphNorm: block per graph (batch is sorted) ----------------
template <int F>
__global__ void graphnorm_k(const float* xin, float* xout, const int* __restrict__ gstart,
                            const float* __restrict__ w, const float* __restrict__ b,
                            const float* __restrict__ a) {
    constexpr int NPB = 256 / F;  // nodes per iteration
    __shared__ float red[256];
    __shared__ float smean[F];
    __shared__ float sscale[F];
    int g = blockIdx.x;
    int s = gstart[g], e = gstart[g + 1];
    int cnt = e - s;
    float cntf = (float)(cnt > 1 ? cnt : 1);
    int tid = threadIdx.x;
    int f = tid % F, r = tid / F;

    // pass 1: mean
    float sum = 0.f;
    for (int i = s + r; i < e; i += NPB) sum += xin[i * F + f];
    red[tid] = sum;
    __syncthreads();
    for (int st = NPB / 2; st > 0; st >>= 1) {
        if (r < st) red[tid] += red[tid + st * F];
        __syncthreads();
    }
    if (tid < F) smean[tid] = red[tid] / cntf;
    __syncthreads();
    float am = a[f] * smean[f];

    // pass 2: var of (x - a*mean)
    float sq = 0.f;
    for (int i = s + r; i < e; i += NPB) {
        float d = xin[i * F + f] - am;
        sq += d * d;
    }
    __syncthreads();
    red[tid] = sq;
    __syncthreads();
    for (int st = NPB / 2; st > 0; st >>= 1) {
        if (r < st) red[tid] += red[tid + st * F];
        __syncthreads();
    }
    if (tid < F) sscale[tid] = w[tid] * rsqrtf(red[tid] / cntf + GN_EPS);
    __syncthreads();
    float sc = sscale[f], bb = b[f];

    // pass 3: write
    for (int i = s + r; i < e; i += NPB) xout[i * F + f] = (xin[i * F + f] - am) * sc + bb;
}

// ---------------- Linear: [N,FIN] @ [FIN,64], block = 4 nodes ----------------
template <int FIN>
__global__ void linear_k(const float* __restrict__ x, const float* __restrict__ W,
                         float* __restrict__ out) {
    __shared__ float sW[FIN * 64];
    __shared__ float sX[4 * FIN];
    int tid = threadIdx.x;
    for (int i = tid; i < FIN * 64; i += 256) sW[i] = W[i];
    int nb = blockIdx.x * 4;
    for (int i = tid; i < 4 * FIN; i += 256) sX[i] = x[nb * FIN + i];
    __syncthreads();
    int r = tid >> 6, f = tid & 63;
    float acc = 0.f;
#pragma unroll
    for (int k = 0; k < FIN; k++) acc += sX[r * FIN + k] * sW[k * 64 + f];
    out[(nb + r) * 64 + f] = acc;
}

// ---------------- Aggregation: one wave per node, lane = feature ----------------
__global__ void aggregate_k(const float* __restrict__ h, const int* __restrict__ rowptr,
                            const int* __restrict__ csr_src, const float* __restrict__ dinv,
                            const float* __restrict__ selfw, const float* __restrict__ bias,
                            float* __restrict__ out) {
    int node = blockIdx.x * 4 + (threadIdx.x >> 6);
    int lane = threadIdx.x & 63;
    float acc = h[node * 64 + lane] * selfw[node];
    float dn = dinv[node];
    int s = rowptr[node], e = rowptr[node + 1];
    for (int j = s; j < e; j++) {
        int u = csr_src[j];
        acc = fmaf(h[u * 64 + lane], dinv[u] * dn, acc);
    }
    float v = acc + bias[lane];
    out[node * 64 + lane] = v > 0.f ? v : 0.f;
}

// ---------------- Pool + MLP head + softmax: block per graph ----------------
__global__ void pool_head_k(const float* __restrict__ x, const int* __restrict__ gstart,
                            const float* __restrict__ Wd, const float* __restrict__ bd,
                            const float* __restrict__ Wo, const float* __restrict__ bo,
                            float* __restrict__ out) {
    __shared__ float red[256];
    __shared__ float sp[64];
    __shared__ float sh[64];
    __shared__ float sl[2];
    int g = blockIdx.x;
    int s = gstart[g], e = gstart[g + 1];
    int cnt = e - s;
    float cntf = (float)(cnt > 1 ? cnt : 1);
    int tid = threadIdx.x;
    int f = tid & 63, r = tid >> 6;
    float sum = 0.f;
    for (int i = s + r; i < e; i += 4) sum += x[i * 64 + f];
    red[tid] = sum;
    __syncthreads();
    for (int st = 2; st > 0; st >>= 1) {
        if (r < st) red[tid] += red[tid + st * 64];
        __syncthreads();
    }
    if (tid < 64) sp[tid] = red[tid] / cntf;
    __syncthreads();
    if (tid < 64) {
        float acc = bd[tid];
        for (int k = 0; k < 64; k++) acc = fmaf(sp[k], Wd[k * 64 + tid], acc);
        sh[tid] = acc > 0.f ? acc : 0.f;
    }
    __syncthreads();
    if (tid < 2) {
        float l = bo[tid];
        for (int k = 0; k < 64; k++) l = fmaf(sh[k], Wo[k * 2 + tid], l);
        sl[tid] = l;
    }
    __syncthreads();
    if (tid < 2) {
        float m = fmaxf(sl[0], sl[1]);
        float e0 = expf(sl[0] - m), e1 = expf(sl[1] - m);
        out[g * 2 + tid] = (tid == 0 ? e0 : e1) / (e0 + e1);
    }
}

extern "C" void kernel_launch(void* const* d_in, const int* in_sizes, int n_in,
                              void* d_out, int out_size, void* d_ws, size_t ws_size,
                              hipStream_t stream) {
    const float* x    = (const float*)d_in[0];
    const int* ei     = (const int*)d_in[1];
    const int* batch  = (const int*)d_in[2];
    const float* gn0w = (const float*)d_in[3];
    const float* gn0b = (const float*)d_in[4];
    const float* gn0a = (const float*)d_in[5];
    const float* W1   = (const float*)d_in[6];
    const float* b1   = (const float*)d_in[7];
    const float* gn1w = (const float*)d_in[8];
    const float* gn1b = (const float*)d_in[9];
    const float* gn1a = (const float*)d_in[10];
    const float* W2   = (const float*)d_in[11];
    const float* b2   = (const float*)d_in[12];
    const float* gn2w = (const float*)d_in[13];
    const float* gn2b = (const float*)d_in[14];
    const float* gn2a = (const float*)d_in[15];
    const float* W3   = (const float*)d_in[16];
    const float* b3   = (const float*)d_in[17];
    const float* Wd   = (const float*)d_in[18];
    const float* bd   = (const float*)d_in[19];
    const float* Wo   = (const float*)d_in[20];
    const float* bo   = (const float*)d_in[21];

    char* p = (char*)d_ws;
    auto alloc = [&](size_t bytes) -> void* {
        void* r = (void*)p;
        p += (bytes + 255) & ~(size_t)255;
        return r;
    };
    float* A       = (float*)alloc((size_t)NB_NODES * 64 * 4);  // also aliases the [N,16] normed input
    float* B       = (float*)alloc((size_t)NB_NODES * 64 * 4);
    int* rowptr    = (int*)alloc((size_t)(NB_NODES + 1) * 4);
    int* deg_in    = (int*)alloc((size_t)NB_NODES * 4);
    int* cursor    = (int*)alloc((size_t)NB_NODES * 4);
    int* csr_src   = (int*)alloc((size_t)NB_EDGES * 4);
    float* dinv    = (float*)alloc((size_t)NB_NODES * 4);
    float* selfw   = (float*)alloc((size_t)NB_NODES * 4);
    int* counts    = (int*)alloc((size_t)NB_GRAPHS * 4);
    int* gstart    = (int*)alloc((size_t)(NB_GRAPHS + 1) * 4);
    int* bsums     = (int*)alloc(128 * 4);
    int* boffs     = (int*)alloc(128 * 4);

    hipMemsetAsync(counts, 0, NB_GRAPHS * 4, stream);
    hipMemsetAsync(deg_in, 0, NB_NODES * 4, stream);
    hipMemsetAsync(cursor, 0, NB_NODES * 4, stream);

    hist_batch_k<<<391, 256, 0, stream>>>(batch, counts);
    hist_deg_k<<<6250, 256, 0, stream>>>(ei + NB_EDGES, deg_in);
    scan_g_k<<<1, 1024, 0, stream>>>(counts, gstart);
    node_deg_k<<<391, 256, 0, stream>>>(deg_in, dinv, selfw);
    scanA_k<<<98, 256, 0, stream>>>(deg_in, bsums);
    scanB_k<<<1, 128, 0, stream>>>(bsums, boffs);
    scanC_k<<<98, 256, 0, stream>>>(deg_in, boffs, rowptr);
    csr_fill_k<<<6250, 256, 0, stream>>>(ei, rowptr, cursor, csr_src);

    // layer 0 norm on raw input (F=16), result into A (as [N,16])
    graphnorm_k<16><<<NB_GRAPHS, 256, 0, stream>>>(x, A, gstart, gn0w, gn0b, gn0a);
    // conv1
    linear_k<16><<<25000, 256, 0, stream>>>(A, W1, B);
    aggregate_k<<<25000, 256, 0, stream>>>(B, rowptr, csr_src, dinv, selfw, b1, A);
    graphnorm_k<64><<<NB_GRAPHS, 256, 0, stream>>>(A, A, gstart, gn1w, gn1b, gn1a);
    // conv2
    linear_k<64><<<25000, 256, 0, stream>>>(A, W2, B);
    aggregate_k<<<25000, 256, 0, stream>>>(B, rowptr, csr_src, dinv, selfw, b2, A);
    graphnorm_k<64><<<NB_GRAPHS, 256, 0, stream>>>(A, A, gstart, gn2w, gn2b, gn2a);
    // conv3
    linear_k<64><<<25000, 256, 0, stream>>>(A, W3, B);
    aggregate_k<<<25000, 256, 0, stream>>>(B, rowptr, csr_src, dinv, selfw, b3, A);
    // pool + head + softmax
    pool_head_k<<<NB_GRAPHS, 256, 0, stream>>>(A, gstart, Wd, bd, Wo, bo, (float*)d_out);
}

// Round 2
// 713.763 us; speedup vs baseline: 1.3785x; 1.3785x over previous
//
#include <hip/hip_runtime.h>
#include <math.h>

#define NB_NODES 100000
#define NB_EDGES 1600000
#define NB_GRAPHS 1000
constexpr float GN_EPS = 1e-5f;

// ---------------- histogram / degree ----------------
__global__ void hist_batch_k(const int* __restrict__ batch, int* __restrict__ counts) {
    int i = blockIdx.x * 256 + threadIdx.x;
    if (i < NB_NODES) atomicAdd(&counts[batch[i]], 1);
}

__global__ void hist_deg_k(const int* __restrict__ dst, int* __restrict__ deg_in) {
    int e = blockIdx.x * 256 + threadIdx.x;
    if (e < NB_EDGES) atomicAdd(&deg_in[dst[e]], 1);
}

__global__ void node_deg_k(const int* __restrict__ deg_in, float* __restrict__ dinv) {
    int i = blockIdx.x * 256 + threadIdx.x;
    if (i < NB_NODES) {
        float d = (float)(deg_in[i] + 1);
        dinv[i] = rsqrtf(d);
    }
}

// ---------------- scans ----------------
__global__ void scan_g_k(const int* __restrict__ counts, int* __restrict__ gstart) {
    __shared__ int s[1024];
    int tid = threadIdx.x;
    int own = (tid < NB_GRAPHS) ? counts[tid] : 0;
    s[tid] = own;
    __syncthreads();
    for (int off = 1; off < 1024; off <<= 1) {
        int t = (tid >= off) ? s[tid - off] : 0;
        __syncthreads();
        s[tid] += t;
        __syncthreads();
    }
    if (tid < NB_GRAPHS) gstart[tid] = s[tid] - own;
    if (tid == 0) gstart[NB_GRAPHS] = NB_NODES;
}

__global__ void scanA_k(const int* __restrict__ deg_in, int* __restrict__ bsums) {
    __shared__ int red[256];
    int tid = threadIdx.x;
    int base = blockIdx.x * 1024 + tid * 4;
    int s = 0;
#pragma unroll
    for (int i = 0; i < 4; i++) {
        int idx = base + i;
        s += (idx < NB_NODES) ? deg_in[idx] : 0;
    }
    red[tid] = s;
    __syncthreads();
    for (int st = 128; st > 0; st >>= 1) {
        if (tid < st) red[tid] += red[tid + st];
        __syncthreads();
    }
    if (tid == 0) bsums[blockIdx.x] = red[0];
}

__global__ void scanB_k(const int* __restrict__ bsums, int* __restrict__ boffs) {
    __shared__ int s[128];
    int tid = threadIdx.x;
    int own = (tid < 98) ? bsums[tid] : 0;
    s[tid] = own;
    __syncthreads();
    for (int off = 1; off < 128; off <<= 1) {
        int t = (tid >= off) ? s[tid - off] : 0;
        __syncthreads();
        s[tid] += t;
        __syncthreads();
    }
    if (tid < 98) boffs[tid] = s[tid] - own;
}

__global__ void scanC_k(const int* __restrict__ deg_in, const int* __restrict__ boffs,
                        int* __restrict__ rowptr) {
    __shared__ int s[256];
    int tid = threadIdx.x;
    int base = blockIdx.x * 1024 + tid * 4;
    int v[4];
    int tsum = 0;
#pragma unroll
    for (int i = 0; i < 4; i++) {
        v[i] = (base + i < NB_NODES) ? deg_in[base + i] : 0;
        tsum += v[i];
    }
    s[tid] = tsum;
    __syncthreads();
    for (int off = 1; off < 256; off <<= 1) {
        int t = (tid >= off) ? s[tid - off] : 0;
        __syncthreads();
        s[tid] += t;
        __syncthreads();
    }
    int run = boffs[blockIdx.x] + s[tid] - tsum;
#pragma unroll
    for (int i = 0; i < 4; i++) {
        if (base + i < NB_NODES) rowptr[base + i] = run;
        run += v[i];
    }
    if (blockIdx.x == 0 && tid == 0) rowptr[NB_NODES] = NB_EDGES;
}

__global__ void csr_fill_k(const int* __restrict__ ei, const int* __restrict__ rowptr,
                           int* __restrict__ cursor, int* __restrict__ csr_src) {
    int e = blockIdx.x * 256 + threadIdx.x;
    if (e < NB_EDGES) {
        int s = ei[e];
        int d = ei[NB_EDGES + e];
        int pos = atomicAdd(&cursor[d], 1);
        csr_src[rowptr[d] + pos] = s;
    }
}

// ---------------- GraphNorm: block per graph (batch is sorted) ----------------
template <int F>
__global__ void graphnorm_k(const float* xin, float* xout, const int* __restrict__ gstart,
                            const float* __restrict__ w, const float* __restrict__ b,
                            const float* __restrict__ a) {
    constexpr int NPB = 256 / F;
    __shared__ float red[256];
    __shared__ float smean[F];
    __shared__ float sscale[F];
    int g = blockIdx.x;
    int s = gstart[g], e = gstart[g + 1];
    int cnt = e - s;
    float cntf = (float)(cnt > 1 ? cnt : 1);
    int tid = threadIdx.x;
    int f = tid % F, r = tid / F;

    float sum = 0.f;
    for (int i = s + r; i < e; i += NPB) sum += xin[i * F + f];
    red[tid] = sum;
    __syncthreads();
    for (int st = NPB / 2; st > 0; st >>= 1) {
        if (r < st) red[tid] += red[tid + st * F];
        __syncthreads();
    }
    if (tid < F) smean[tid] = red[tid] / cntf;
    __syncthreads();
    float am = a[f] * smean[f];

    float sq = 0.f;
    for (int i = s + r; i < e; i += NPB) {
        float d = xin[i * F + f] - am;
        sq += d * d;
    }
    __syncthreads();
    red[tid] = sq;
    __syncthreads();
    for (int st = NPB / 2; st > 0; st >>= 1) {
        if (r < st) red[tid] += red[tid + st * F];
        __syncthreads();
    }
    if (tid < F) sscale[tid] = w[tid] * rsqrtf(red[tid] / cntf + GN_EPS);
    __syncthreads();
    float sc = sscale[f], bb = b[f];

    for (int i = s + r; i < e; i += NPB) xout[i * F + f] = (xin[i * F + f] - am) * sc + bb;
}

// ---------------- Linear: [N,FIN] @ [FIN,64], output scaled by dinv[node] ----------------
template <int FIN>
__global__ void linear_k(const float* __restrict__ x, const float* __restrict__ W,
                         const float* __restrict__ dinv, float* __restrict__ out) {
    __shared__ float sW[FIN * 64];
    __shared__ float sX[4 * FIN];
    int tid = threadIdx.x;
    for (int i = tid; i < FIN * 64; i += 256) sW[i] = W[i];
    int nb = blockIdx.x * 4;
    for (int i = tid; i < 4 * FIN; i += 256) sX[i] = x[nb * FIN + i];
    __syncthreads();
    int r = tid >> 6, f = tid & 63;
    float acc = 0.f;
#pragma unroll
    for (int k = 0; k < FIN; k++) acc += sX[r * FIN + k] * sW[k * 64 + f];
    out[(nb + r) * 64 + f] = acc * dinv[nb + r];
}

// ---------------- Aggregation: one wave per node, lane = feature ----------------
// hs[n] = (x@W)[n] * dinv[n].  out = relu(dinv[dst]*(hs[dst] + sum_src hs[src]) + bias)
__global__ void aggregate_k(const float* __restrict__ hs, const int* __restrict__ rowptr,
                            const int* __restrict__ csr_src, const float* __restrict__ dinv,
                            const float* __restrict__ bias, float* __restrict__ out) {
    int node = blockIdx.x * 4 + (threadIdx.x >> 6);
    int lane = threadIdx.x & 63;
    int s = rowptr[node], e = rowptr[node + 1];
    float dn = dinv[node];
    float a0 = hs[(size_t)node * 64 + lane];
    float a1 = 0.f, a2 = 0.f, a3 = 0.f, a4 = 0.f, a5 = 0.f, a6 = 0.f, a7 = 0.f;
    int j = s;
    for (; j + 8 <= e; j += 8) {
        int u0 = csr_src[j + 0], u1 = csr_src[j + 1], u2 = csr_src[j + 2], u3 = csr_src[j + 3];
        int u4 = csr_src[j + 4], u5 = csr_src[j + 5], u6 = csr_src[j + 6], u7 = csr_src[j + 7];
        a0 += hs[(size_t)u0 * 64 + lane];
        a1 += hs[(size_t)u1 * 64 + lane];
        a2 += hs[(size_t)u2 * 64 + lane];
        a3 += hs[(size_t)u3 * 64 + lane];
        a4 += hs[(size_t)u4 * 64 + lane];
        a5 += hs[(size_t)u5 * 64 + lane];
        a6 += hs[(size_t)u6 * 64 + lane];
        a7 += hs[(size_t)u7 * 64 + lane];
    }
    if (j + 4 <= e) {
        int u0 = csr_src[j + 0], u1 = csr_src[j + 1], u2 = csr_src[j + 2], u3 = csr_src[j + 3];
        a0 += hs[(size_t)u0 * 64 + lane];
        a1 += hs[(size_t)u1 * 64 + lane];
        a2 += hs[(size_t)u2 * 64 + lane];
        a3 += hs[(size_t)u3 * 64 + lane];
        j += 4;
    }
    for (; j < e; j++) a0 += hs[(size_t)csr_src[j] * 64 + lane];
    float v = ((a0 + a1) + (a2 + a3) + ((a4 + a5) + (a6 + a7))) * dn + bias[lane];
    out[(size_t)node * 64 + lane] = v > 0.f ? v : 0.f;
}

// ---------------- Pool + MLP head + softmax: block per graph ----------------
__global__ void pool_head_k(const float* __restrict__ x, const int* __restrict__ gstart,
                            const float* __restrict__ Wd, const float* __restrict__ bd,
                            const float* __restrict__ Wo, const float* __restrict__ bo,
                            float* __restrict__ out) {
    __shared__ float red[256];
    __shared__ float sp[64];
    __shared__ float sh[64];
    __shared__ float sl[2];
    int g = blockIdx.x;
    int s = gstart[g], e = gstart[g + 1];
    int cnt = e - s;
    float cntf = (float)(cnt > 1 ? cnt : 1);
    int tid = threadIdx.x;
    int f = tid & 63, r = tid >> 6;
    float sum = 0.f;
    for (int i = s + r; i < e; i += 4) sum += x[i * 64 + f];
    red[tid] = sum;
    __syncthreads();
    for (int st = 2; st > 0; st >>= 1) {
        if (r < st) red[tid] += red[tid + st * 64];
        __syncthreads();
    }
    if (tid < 64) sp[tid] = red[tid] / cntf;
    __syncthreads();
    if (tid < 64) {
        float acc = bd[tid];
        for (int k = 0; k < 64; k++) acc = fmaf(sp[k], Wd[k * 64 + tid], acc);
        sh[tid] = acc > 0.f ? acc : 0.f;
    }
    __syncthreads();
    if (tid < 2) {
        float l = bo[tid];
        for (int k = 0; k < 64; k++) l = fmaf(sh[k], Wo[k * 2 + tid], l);
        sl[tid] = l;
    }
    __syncthreads();
    if (tid < 2) {
        float m = fmaxf(sl[0], sl[1]);
        float e0 = expf(sl[0] - m), e1 = expf(sl[1] - m);
        out[g * 2 + tid] = (tid == 0 ? e0 : e1) / (e0 + e1);
    }
}

extern "C" void kernel_launch(void* const* d_in, const int* in_sizes, int n_in,
                              void* d_out, int out_size, void* d_ws, size_t ws_size,
                              hipStream_t stream) {
    const float* x    = (const float*)d_in[0];
    const int* ei     = (const int*)d_in[1];
    const int* batch  = (const int*)d_in[2];
    const float* gn0w = (const float*)d_in[3];
    const float* gn0b = (const float*)d_in[4];
    const float* gn0a = (const float*)d_in[5];
    const float* W1   = (const float*)d_in[6];
    const float* b1   = (const float*)d_in[7];
    const float* gn1w = (const float*)d_in[8];
    const float* gn1b = (const float*)d_in[9];
    const float* gn1a = (const float*)d_in[10];
    const float* W2   = (const float*)d_in[11];
    const float* b2   = (const float*)d_in[12];
    const float* gn2w = (const float*)d_in[13];
    const float* gn2b = (const float*)d_in[14];
    const float* gn2a = (const float*)d_in[15];
    const float* W3   = (const float*)d_in[16];
    const float* b3   = (const float*)d_in[17];
    const float* Wd   = (const float*)d_in[18];
    const float* bd   = (const float*)d_in[19];
    const float* Wo   = (const float*)d_in[20];
    const float* bo   = (const float*)d_in[21];

    char* p = (char*)d_ws;
    auto alloc = [&](size_t bytes) -> void* {
        void* r = (void*)p;
        p += (bytes + 255) & ~(size_t)255;
        return r;
    };
    float* A       = (float*)alloc((size_t)NB_NODES * 64 * 4);
    float* B       = (float*)alloc((size_t)NB_NODES * 64 * 4);
    int* rowptr    = (int*)alloc((size_t)(NB_NODES + 1) * 4);
    int* deg_in    = (int*)alloc((size_t)NB_NODES * 4);
    int* cursor    = (int*)alloc((size_t)NB_NODES * 4);
    int* csr_src   = (int*)alloc((size_t)NB_EDGES * 4);
    float* dinv    = (float*)alloc((size_t)NB_NODES * 4);
    int* counts    = (int*)alloc((size_t)NB_GRAPHS * 4);
    int* gstart    = (int*)alloc((size_t)(NB_GRAPHS + 1) * 4);
    int* bsums     = (int*)alloc(128 * 4);
    int* boffs     = (int*)alloc(128 * 4);

    hipMemsetAsync(counts, 0, NB_GRAPHS * 4, stream);
    hipMemsetAsync(deg_in, 0, NB_NODES * 4, stream);
    hipMemsetAsync(cursor, 0, NB_NODES * 4, stream);

    hist_batch_k<<<391, 256, 0, stream>>>(batch, counts);
    hist_deg_k<<<6250, 256, 0, stream>>>(ei + NB_EDGES, deg_in);
    scan_g_k<<<1, 1024, 0, stream>>>(counts, gstart);
    node_deg_k<<<391, 256, 0, stream>>>(deg_in, dinv);
    scanA_k<<<98, 256, 0, stream>>>(deg_in, bsums);
    scanB_k<<<1, 128, 0, stream>>>(bsums, boffs);
    scanC_k<<<98, 256, 0, stream>>>(deg_in, boffs, rowptr);
    csr_fill_k<<<6250, 256, 0, stream>>>(ei, rowptr, cursor, csr_src);

    graphnorm_k<16><<<NB_GRAPHS, 256, 0, stream>>>(x, A, gstart, gn0w, gn0b, gn0a);
    // conv1
    linear_k<16><<<25000, 256, 0, stream>>>(A, W1, dinv, B);
    aggregate_k<<<25000, 256, 0, stream>>>(B, rowptr, csr_src, dinv, b1, A);
    graphnorm_k<64><<<NB_GRAPHS, 256, 0, stream>>>(A, A, gstart, gn1w, gn1b, gn1a);
    // conv2
    linear_k<64><<<25000, 256, 0, stream>>>(A, W2, dinv, B);
    aggregate_k<<<25000, 256, 0, stream>>>(B, rowptr, csr_src, dinv, b2, A);
    graphnorm_k<64><<<NB_GRAPHS, 256, 0, stream>>>(A, A, gstart, gn2w, gn2b, gn2a);
    // conv3
    linear_k<64><<<25000, 256, 0, stream>>>(A, W3, dinv, B);
    aggregate_k<<<25000, 256, 0, stream>>>(B, rowptr, csr_src, dinv, b3, A);
    // pool + head + softmax
    pool_head_k<<<NB_GRAPHS, 256, 0, stream>>>(A, gstart, Wd, bd, Wo, bo, (float*)d_out);
}

// Round 3
// 710.027 us; speedup vs baseline: 1.3858x; 1.0053x over previous
//
#include <hip/hip_runtime.h>
#include <math.h>

#define NB_NODES 100000
#define NB_EDGES 1600000
#define NB_GRAPHS 1000
#define CAP 232  // max graph size held in LDS; mean=100, sigma~10 -> 232 is +13 sigma
constexpr float GN_EPS = 1e-5f;

// ---------------- gstart: binary search on sorted batch ----------------
__global__ void gstart_k(const int* __restrict__ batch, int* __restrict__ gstart) {
    int g = blockIdx.x * 256 + threadIdx.x;
    if (g <= NB_GRAPHS) {
        int lo = 0, hi = NB_NODES;
        while (lo < hi) {
            int mid = (lo + hi) >> 1;
            if (batch[mid] < g) lo = mid + 1; else hi = mid;
        }
        gstart[g] = lo;
    }
}

// ---------------- degree histogram + per-edge rank ----------------
__global__ void hist_deg_rank_k(const int* __restrict__ dst, int* __restrict__ deg_in,
                                int* __restrict__ rk) {
    int e = blockIdx.x * 256 + threadIdx.x;
    if (e < NB_EDGES) rk[e] = atomicAdd(&deg_in[dst[e]], 1);
}

__global__ void node_deg_k(const int* __restrict__ deg_in, float* __restrict__ dinv) {
    int i = blockIdx.x * 256 + threadIdx.x;
    if (i < NB_NODES) dinv[i] = rsqrtf((float)(deg_in[i] + 1));
}

// ---------------- rowptr scans ----------------
__global__ void scanA_k(const int* __restrict__ deg_in, int* __restrict__ bsums) {
    __shared__ int red[256];
    int tid = threadIdx.x;
    int base = blockIdx.x * 1024 + tid * 4;
    int s = 0;
#pragma unroll
    for (int i = 0; i < 4; i++) s += (base + i < NB_NODES) ? deg_in[base + i] : 0;
    red[tid] = s;
    __syncthreads();
    for (int st = 128; st > 0; st >>= 1) {
        if (tid < st) red[tid] += red[tid + st];
        __syncthreads();
    }
    if (tid == 0) bsums[blockIdx.x] = red[0];
}

__global__ void scanB_k(const int* __restrict__ bsums, int* __restrict__ boffs) {
    __shared__ int s[128];
    int tid = threadIdx.x;
    int own = (tid < 98) ? bsums[tid] : 0;
    s[tid] = own;
    __syncthreads();
    for (int off = 1; off < 128; off <<= 1) {
        int t = (tid >= off) ? s[tid - off] : 0;
        __syncthreads();
        s[tid] += t;
        __syncthreads();
    }
    if (tid < 98) boffs[tid] = s[tid] - own;
}

__global__ void scanC_k(const int* __restrict__ deg_in, const int* __restrict__ boffs,
                        int* __restrict__ rowptr) {
    __shared__ int s[256];
    int tid = threadIdx.x;
    int base = blockIdx.x * 1024 + tid * 4;
    int v[4];
    int tsum = 0;
#pragma unroll
    for (int i = 0; i < 4; i++) {
        v[i] = (base + i < NB_NODES) ? deg_in[base + i] : 0;
        tsum += v[i];
    }
    s[tid] = tsum;
    __syncthreads();
    for (int off = 1; off < 256; off <<= 1) {
        int t = (tid >= off) ? s[tid - off] : 0;
        __syncthreads();
        s[tid] += t;
        __syncthreads();
    }
    int run = boffs[blockIdx.x] + s[tid] - tsum;
#pragma unroll
    for (int i = 0; i < 4; i++) {
        if (base + i < NB_NODES) rowptr[base + i] = run;
        run += v[i];
    }
    if (blockIdx.x == 0 && tid == 0) rowptr[NB_NODES] = NB_EDGES;
}

__global__ void csr_fill_k(const int* __restrict__ ei, const int* __restrict__ rowptr,
                           const int* __restrict__ rk, int* __restrict__ csr_src) {
    int e = blockIdx.x * 256 + threadIdx.x;
    if (e < NB_EDGES) {
        int sidx = ei[e];
        int d = ei[NB_EDGES + e];
        csr_src[rowptr[d] + rk[e]] = sidx;
    }
}

// ---------------- gather-aggregate one node row (wave-per-node, lane=feature) -----
__device__ __forceinline__ float gather_sum(const float* __restrict__ hs,
                                            const int* __restrict__ csr,
                                            int s, int e, int lane, float a0) {
    float a1 = 0.f, a2 = 0.f, a3 = 0.f, a4 = 0.f, a5 = 0.f, a6 = 0.f, a7 = 0.f;
    int j = s;
    for (; j + 8 <= e; j += 8) {
        int u0 = csr[j], u1 = csr[j + 1], u2 = csr[j + 2], u3 = csr[j + 3];
        int u4 = csr[j + 4], u5 = csr[j + 5], u6 = csr[j + 6], u7 = csr[j + 7];
        a0 += hs[(size_t)u0 * 64 + lane];
        a1 += hs[(size_t)u1 * 64 + lane];
        a2 += hs[(size_t)u2 * 64 + lane];
        a3 += hs[(size_t)u3 * 64 + lane];
        a4 += hs[(size_t)u4 * 64 + lane];
        a5 += hs[(size_t)u5 * 64 + lane];
        a6 += hs[(size_t)u6 * 64 + lane];
        a7 += hs[(size_t)u7 * 64 + lane];
    }
    if (j + 4 <= e) {
        int u0 = csr[j], u1 = csr[j + 1], u2 = csr[j + 2], u3 = csr[j + 3];
        a0 += hs[(size_t)u0 * 64 + lane];
        a1 += hs[(size_t)u1 * 64 + lane];
        a2 += hs[(size_t)u2 * 64 + lane];
        a3 += hs[(size_t)u3 * 64 + lane];
        j += 4;
    }
    for (; j < e; j++) a0 += hs[(size_t)csr[j] * 64 + lane];
    return ((a0 + a1) + (a2 + a3)) + ((a4 + a5) + (a6 + a7));
}

// ---------------- layer0: GraphNorm(16) + linear 16->64 (block per graph) ---------
__device__ __forceinline__ void l0_body(float* rows, int cnt, int s,
    const float* __restrict__ x, const float* __restrict__ gw,
    const float* __restrict__ gb, const float* __restrict__ ga,
    const float* sW, const float* __restrict__ dinv, float* __restrict__ hs_out,
    float* red, float* sstat, float* sscale, int tid) {
    int f = tid & 15, r = tid >> 4;        // 32 rows in parallel for GN phases
    int lane = tid & 63, wid = tid >> 6;   // 8 waves for linear phase
    float cntf = (float)(cnt > 1 ? cnt : 1);
    float sum = 0.f;
    for (int i = r; i < cnt; i += 32) {
        float v = x[(size_t)(s + i) * 16 + f];
        rows[i * 16 + f] = v;
        sum += v;
    }
    red[tid] = sum;
    __syncthreads();
    for (int st = 16; st > 0; st >>= 1) {
        if (r < st) red[tid] += red[tid + st * 16];
        __syncthreads();
    }
    if (tid < 16) sstat[tid] = ga[tid] * (red[tid] / cntf);
    __syncthreads();
    float am = sstat[f];
    float sq = 0.f;
    for (int i = r; i < cnt; i += 32) {
        float d = rows[i * 16 + f] - am;
        sq += d * d;
    }
    __syncthreads();
    red[tid] = sq;
    __syncthreads();
    for (int st = 16; st > 0; st >>= 1) {
        if (r < st) red[tid] += red[tid + st * 16];
        __syncthreads();
    }
    if (tid < 16) sscale[tid] = gw[tid] * rsqrtf(red[tid] / cntf + GN_EPS);
    __syncthreads();
    float sc = sscale[f], bb = gb[f];
    for (int i = r; i < cnt; i += 32) rows[i * 16 + f] = (rows[i * 16 + f] - am) * sc + bb;
    __syncthreads();
    for (int i = wid; i < cnt; i += 8) {
        float acc = 0.f;
#pragma unroll
        for (int k = 0; k < 16; k++) acc = fmaf(rows[i * 16 + k], sW[k * 64 + lane], acc);
        hs_out[(size_t)(s + i) * 64 + lane] = acc * dinv[s + i];
    }
}

__global__ __launch_bounds__(512) void layer0_k(const float* __restrict__ x,
    const int* __restrict__ gstart, const float* __restrict__ gw,
    const float* __restrict__ gb, const float* __restrict__ ga,
    const float* __restrict__ W, const float* __restrict__ dinv,
    float* __restrict__ hs_out, float* __restrict__ spill16) {
    __shared__ float sRows[CAP * 16];
    __shared__ float sW[16 * 64];
    __shared__ float red[512];
    __shared__ float sstat[16], sscale[16];
    int tid = threadIdx.x;
    int g = blockIdx.x;
    int s = gstart[g], e = gstart[g + 1], cnt = e - s;
    for (int i = tid; i < 16 * 64; i += 512) sW[i] = W[i];
    __syncthreads();
    if (cnt <= CAP)
        l0_body(sRows, cnt, s, x, gw, gb, ga, sW, dinv, hs_out, red, sstat, sscale, tid);
    else
        l0_body(spill16 + (size_t)s * 16, cnt, s, x, gw, gb, ga, sW, dinv, hs_out, red, sstat, sscale, tid);
}

// ------- mid layer: aggregate + bias + relu + GraphNorm(64) + linear 64x64 --------
__device__ __forceinline__ void mid_body(float* rows, int cnt, int s,
    const float* __restrict__ hs_in, const int* __restrict__ rowptr,
    const int* __restrict__ csr_src, const float* __restrict__ dinv,
    const float* __restrict__ bconv, const float* __restrict__ gw,
    const float* __restrict__ gb, const float* __restrict__ ga,
    const float* sW, float* __restrict__ hs_out,
    float* red, float* sstat, float* sscale, int tid) {
    int lane = tid & 63, wid = tid >> 6;
    float cntf = (float)(cnt > 1 ? cnt : 1);
    // phase 1: aggregate rows of my graph
    for (int n = s + wid; n < s + cnt; n += 8) {
        int rs = rowptr[n], re = rowptr[n + 1];
        float self = hs_in[(size_t)n * 64 + lane];
        float v = gather_sum(hs_in, csr_src, rs, re, lane, self) * dinv[n] + bconv[lane];
        rows[(n - s) * 64 + lane] = v > 0.f ? v : 0.f;
    }
    __syncthreads();
    // phase 2: GraphNorm stats
    float sum = 0.f;
    for (int i = wid; i < cnt; i += 8) sum += rows[i * 64 + lane];
    red[tid] = sum;
    __syncthreads();
    for (int st = 4; st > 0; st >>= 1) {
        if (wid < st) red[tid] += red[tid + st * 64];
        __syncthreads();
    }
    if (tid < 64) sstat[tid] = ga[tid] * (red[tid] / cntf);
    __syncthreads();
    float am = sstat[lane];
    float sq = 0.f;
    for (int i = wid; i < cnt; i += 8) {
        float d = rows[i * 64 + lane] - am;
        sq += d * d;
    }
    __syncthreads();
    red[tid] = sq;
    __syncthreads();
    for (int st = 4; st > 0; st >>= 1) {
        if (wid < st) red[tid] += red[tid + st * 64];
        __syncthreads();
    }
    if (tid < 64) sscale[tid] = gw[tid] * rsqrtf(red[tid] / cntf + GN_EPS);
    __syncthreads();
    float sc = sscale[lane], bb = gb[lane];
    // phase 3: normalize in place
    for (int i = wid; i < cnt; i += 8) rows[i * 64 + lane] = (rows[i * 64 + lane] - am) * sc + bb;
    __syncthreads();
    // phase 4: linear 64x64 + dinv prescale for next layer
    for (int i = wid; i < cnt; i += 8) {
        float acc = 0.f;
#pragma unroll
        for (int k = 0; k < 64; k++) acc = fmaf(rows[i * 64 + k], sW[k * 64 + lane], acc);
        hs_out[(size_t)(s + i) * 64 + lane] = acc * dinv[s + i];
    }
}

__global__ __launch_bounds__(512) void layer_mid_k(const float* __restrict__ hs_in,
    const int* __restrict__ rowptr, const int* __restrict__ csr_src,
    const float* __restrict__ dinv, const float* __restrict__ bconv,
    const int* __restrict__ gstart, const float* __restrict__ gw,
    const float* __restrict__ gb, const float* __restrict__ ga,
    const float* __restrict__ W, float* __restrict__ hs_out) {
    __shared__ float sRows[CAP * 64];  // 59.4 KB
    __shared__ float sW[64 * 64];      // 16 KB
    __shared__ float red[512];
    __shared__ float sstat[64], sscale[64];
    int tid = threadIdx.x;
    int g = blockIdx.x;
    int s = gstart[g], e = gstart[g + 1], cnt = e - s;
    for (int i = tid; i < 64 * 64; i += 512) sW[i] = W[i];
    __syncthreads();
    if (cnt <= CAP)
        mid_body(sRows, cnt, s, hs_in, rowptr, csr_src, dinv, bconv, gw, gb, ga, sW,
                 hs_out, red, sstat, sscale, tid);
    else  // fallback: rows live in hs_out region (in-place safe: waves own disjoint rows)
        mid_body(hs_out + (size_t)s * 64, cnt, s, hs_in, rowptr, csr_src, dinv, bconv,
                 gw, gb, ga, sW, hs_out, red, sstat, sscale, tid);
}

// ------- last layer: aggregate + bias + relu + mean-pool + MLP head + softmax -----
__global__ __launch_bounds__(512) void layer_last_k(const float* __restrict__ hs_in,
    const int* __restrict__ rowptr, const int* __restrict__ csr_src,
    const float* __restrict__ dinv, const float* __restrict__ bconv,
    const int* __restrict__ gstart, const float* __restrict__ Wd,
    const float* __restrict__ bd, const float* __restrict__ Wo,
    const float* __restrict__ bo, float* __restrict__ out) {
    __shared__ float red[512];
    __shared__ float sp[64];
    __shared__ float sh[64];
    __shared__ float sl[2];
    int tid = threadIdx.x, lane = tid & 63, wid = tid >> 6;
    int g = blockIdx.x;
    int s = gstart[g], e = gstart[g + 1], cnt = e - s;
    float cntf = (float)(cnt > 1 ? cnt : 1);
    float psum = 0.f;
    for (int n = s + wid; n < e; n += 8) {
        int rs = rowptr[n], re = rowptr[n + 1];
        float self = hs_in[(size_t)n * 64 + lane];
        float v = gather_sum(hs_in, csr_src, rs, re, lane, self) * dinv[n] + bconv[lane];
        psum += v > 0.f ? v : 0.f;
    }
    red[tid] = psum;
    __syncthreads();
    for (int st = 4; st > 0; st >>= 1) {
        if (wid < st) red[tid] += red[tid + st * 64];
        __syncthreads();
    }
    if (tid < 64) sp[tid] = red[tid] / cntf;
    __syncthreads();
    if (tid < 64) {
        float acc = bd[tid];
        for (int k = 0; k < 64; k++) acc = fmaf(sp[k], Wd[k * 64 + tid], acc);
        sh[tid] = acc > 0.f ? acc : 0.f;
    }
    __syncthreads();
    if (tid < 2) {
        float l = bo[tid];
        for (int k = 0; k < 64; k++) l = fmaf(sh[k], Wo[k * 2 + tid], l);
        sl[tid] = l;
    }
    __syncthreads();
    if (tid < 2) {
        float m = fmaxf(sl[0], sl[1]);
        float e0 = expf(sl[0] - m), e1 = expf(sl[1] - m);
        out[g * 2 + tid] = (tid == 0 ? e0 : e1) / (e0 + e1);
    }
}

extern "C" void kernel_launch(void* const* d_in, const int* in_sizes, int n_in,
                              void* d_out, int out_size, void* d_ws, size_t ws_size,
                              hipStream_t stream) {
    const float* x    = (const float*)d_in[0];
    const int* ei     = (const int*)d_in[1];
    const int* batch  = (const int*)d_in[2];
    const float* gn0w = (const float*)d_in[3];
    const float* gn0b = (const float*)d_in[4];
    const float* gn0a = (const float*)d_in[5];
    const float* W1   = (const float*)d_in[6];
    const float* b1   = (const float*)d_in[7];
    const float* gn1w = (const float*)d_in[8];
    const float* gn1b = (const float*)d_in[9];
    const float* gn1a = (const float*)d_in[10];
    const float* W2   = (const float*)d_in[11];
    const float* b2   = (const float*)d_in[12];
    const float* gn2w = (const float*)d_in[13];
    const float* gn2b = (const float*)d_in[14];
    const float* gn2a = (const float*)d_in[15];
    const float* W3   = (const float*)d_in[16];
    const float* b3   = (const float*)d_in[17];
    const float* Wd   = (const float*)d_in[18];
    const float* bd   = (const float*)d_in[19];
    const float* Wo   = (const float*)d_in[20];
    const float* bo   = (const float*)d_in[21];

    char* p = (char*)d_ws;
    auto alloc = [&](size_t bytes) -> void* {
        void* r = (void*)p;
        p += (bytes + 255) & ~(size_t)255;
        return r;
    };
    float* A       = (float*)alloc((size_t)NB_NODES * 64 * 4);
    float* B       = (float*)alloc((size_t)NB_NODES * 64 * 4);
    int* rowptr    = (int*)alloc((size_t)(NB_NODES + 1) * 4);
    int* deg_in    = (int*)alloc((size_t)NB_NODES * 4);
    int* rk        = (int*)alloc((size_t)NB_EDGES * 4);
    int* csr_src   = (int*)alloc((size_t)NB_EDGES * 4);
    float* dinv    = (float*)alloc((size_t)NB_NODES * 4);
    int* gstart    = (int*)alloc((size_t)(NB_GRAPHS + 1) * 4);
    int* bsums     = (int*)alloc(128 * 4);
    int* boffs     = (int*)alloc(128 * 4);
    float* spill16 = (float*)alloc((size_t)NB_NODES * 16 * 4);

    hipMemsetAsync(deg_in, 0, NB_NODES * 4, stream);

    gstart_k<<<4, 256, 0, stream>>>(batch, gstart);
    hist_deg_rank_k<<<6250, 256, 0, stream>>>(ei + NB_EDGES, deg_in, rk);
    node_deg_k<<<391, 256, 0, stream>>>(deg_in, dinv);
    scanA_k<<<98, 256, 0, stream>>>(deg_in, bsums);
    scanB_k<<<1, 128, 0, stream>>>(bsums, boffs);
    scanC_k<<<98, 256, 0, stream>>>(deg_in, boffs, rowptr);
    csr_fill_k<<<6250, 256, 0, stream>>>(ei, rowptr, rk, csr_src);

    layer0_k<<<NB_GRAPHS, 512, 0, stream>>>(x, gstart, gn0w, gn0b, gn0a, W1, dinv, B, spill16);
    layer_mid_k<<<NB_GRAPHS, 512, 0, stream>>>(B, rowptr, csr_src, dinv, b1, gstart,
                                               gn1w, gn1b, gn1a, W2, A);
    layer_mid_k<<<NB_GRAPHS, 512, 0, stream>>>(A, rowptr, csr_src, dinv, b2, gstart,
                                               gn2w, gn2b, gn2a, W3, B);
    layer_last_k<<<NB_GRAPHS, 512, 0, stream>>>(B, rowptr, csr_src, dinv, b3, gstart,
                                                Wd, bd, Wo, bo, (float*)d_out);
}

// Round 4
// 480.677 us; speedup vs baseline: 2.0470x; 1.4771x over previous
//
#include <hip/hip_runtime.h>
#include <math.h>

#define NB_NODES 100000
#define NB_EDGES 1600000
#define NB_GRAPHS 1000
#define CAP 232
constexpr float GN_EPS = 1e-5f;

// ---------------- gstart: binary search on sorted batch ----------------
__global__ void gstart_k(const int* __restrict__ batch, int* __restrict__ gstart) {
    int g = blockIdx.x * 256 + threadIdx.x;
    if (g <= NB_GRAPHS) {
        int lo = 0, hi = NB_NODES;
        while (lo < hi) {
            int mid = (lo + hi) >> 1;
            if (batch[mid] < g) lo = mid + 1; else hi = mid;
        }
        gstart[g] = lo;
    }
}

// ---------------- degree histogram + per-edge rank ----------------
__global__ void hist_deg_rank_k(const int* __restrict__ dst, int* __restrict__ deg_in,
                                int* __restrict__ rk) {
    int e = blockIdx.x * 256 + threadIdx.x;
    if (e < NB_EDGES) rk[e] = atomicAdd(&deg_in[dst[e]], 1);
}

__global__ void node_deg_k(const int* __restrict__ deg_in, float* __restrict__ dinv) {
    int i = blockIdx.x * 256 + threadIdx.x;
    if (i < NB_NODES) dinv[i] = rsqrtf((float)(deg_in[i] + 1));
}

// ---------------- rowptr scans ----------------
__global__ void scanA_k(const int* __restrict__ deg_in, int* __restrict__ bsums) {
    __shared__ int red[256];
    int tid = threadIdx.x;
    int base = blockIdx.x * 1024 + tid * 4;
    int s = 0;
#pragma unroll
    for (int i = 0; i < 4; i++) s += (base + i < NB_NODES) ? deg_in[base + i] : 0;
    red[tid] = s;
    __syncthreads();
    for (int st = 128; st > 0; st >>= 1) {
        if (tid < st) red[tid] += red[tid + st];
        __syncthreads();
    }
    if (tid == 0) bsums[blockIdx.x] = red[0];
}

__global__ void scanB_k(const int* __restrict__ bsums, int* __restrict__ boffs) {
    __shared__ int s[128];
    int tid = threadIdx.x;
    int own = (tid < 98) ? bsums[tid] : 0;
    s[tid] = own;
    __syncthreads();
    for (int off = 1; off < 128; off <<= 1) {
        int t = (tid >= off) ? s[tid - off] : 0;
        __syncthreads();
        s[tid] += t;
        __syncthreads();
    }
    if (tid < 98) boffs[tid] = s[tid] - own;
}

__global__ void scanC_k(const int* __restrict__ deg_in, const int* __restrict__ boffs,
                        int* __restrict__ rowptr) {
    __shared__ int s[256];
    int tid = threadIdx.x;
    int base = blockIdx.x * 1024 + tid * 4;
    int v[4];
    int tsum = 0;
#pragma unroll
    for (int i = 0; i < 4; i++) {
        v[i] = (base + i < NB_NODES) ? deg_in[base + i] : 0;
        tsum += v[i];
    }
    s[tid] = tsum;
    __syncthreads();
    for (int off = 1; off < 256; off <<= 1) {
        int t = (tid >= off) ? s[tid - off] : 0;
        __syncthreads();
        s[tid] += t;
        __syncthreads();
    }
    int run = boffs[blockIdx.x] + s[tid] - tsum;
#pragma unroll
    for (int i = 0; i < 4; i++) {
        if (base + i < NB_NODES) rowptr[base + i] = run;
        run += v[i];
    }
    if (blockIdx.x == 0 && tid == 0) rowptr[NB_NODES] = NB_EDGES;
}

__global__ void csr_fill_k(const int* __restrict__ ei, const int* __restrict__ rowptr,
                           const int* __restrict__ rk, int* __restrict__ csr_src) {
    int e = blockIdx.x * 256 + threadIdx.x;
    if (e < NB_EDGES) {
        int sidx = ei[e];
        int d = ei[NB_EDGES + e];
        csr_src[rowptr[d] + rk[e]] = sidx;
    }
}

// --------- aggregate: wave per node, 16 lanes x float4, 4 edges per instr ---------
// hs rows are prescaled by dinv[src]. out = relu(dinv[dst]*(self + sum_src) + bias)
__global__ __launch_bounds__(256) void aggregate4_k(const float* __restrict__ hs,
    const int* __restrict__ rowptr, const int* __restrict__ csr_src,
    const float* __restrict__ dinv, const float* __restrict__ bias,
    float* __restrict__ out) {
    const float4* hs4 = (const float4*)hs;
    int node = blockIdx.x * 4 + (threadIdx.x >> 6);
    int lane = threadIdx.x & 63;
    int f4 = lane & 15;   // feature quad: features [f4*4, f4*4+4)
    int e4 = lane >> 4;   // edge slot 0..3
    int s = rowptr[node], e = rowptr[node + 1];
    float4 a0 = {0.f, 0.f, 0.f, 0.f}, a1 = a0, a2 = a0, a3 = a0;
    if (e4 == 0) a0 = hs4[(size_t)node * 16 + f4];  // self term once
    int j = s;
    for (; j + 16 <= e; j += 16) {
        int u0 = csr_src[j + e4];
        int u1 = csr_src[j + 4 + e4];
        int u2 = csr_src[j + 8 + e4];
        int u3 = csr_src[j + 12 + e4];
        float4 v0 = hs4[(size_t)u0 * 16 + f4];
        float4 v1 = hs4[(size_t)u1 * 16 + f4];
        float4 v2 = hs4[(size_t)u2 * 16 + f4];
        float4 v3 = hs4[(size_t)u3 * 16 + f4];
        a0.x += v0.x; a0.y += v0.y; a0.z += v0.z; a0.w += v0.w;
        a1.x += v1.x; a1.y += v1.y; a1.z += v1.z; a1.w += v1.w;
        a2.x += v2.x; a2.y += v2.y; a2.z += v2.z; a2.w += v2.w;
        a3.x += v3.x; a3.y += v3.y; a3.z += v3.z; a3.w += v3.w;
    }
    for (; j + 4 <= e; j += 4) {
        int u = csr_src[j + e4];
        float4 v = hs4[(size_t)u * 16 + f4];
        a0.x += v.x; a0.y += v.y; a0.z += v.z; a0.w += v.w;
    }
    if (j + e4 < e) {
        int u = csr_src[j + e4];
        float4 v = hs4[(size_t)u * 16 + f4];
        a1.x += v.x; a1.y += v.y; a1.z += v.z; a1.w += v.w;
    }
    float4 t;
    t.x = (a0.x + a1.x) + (a2.x + a3.x);
    t.y = (a0.y + a1.y) + (a2.y + a3.y);
    t.z = (a0.z + a1.z) + (a2.z + a3.z);
    t.w = (a0.w + a1.w) + (a2.w + a3.w);
    // reduce across the 4 edge-slot groups (lanes differing in bits 4,5)
    t.x += __shfl_xor(t.x, 16, 64); t.y += __shfl_xor(t.y, 16, 64);
    t.z += __shfl_xor(t.z, 16, 64); t.w += __shfl_xor(t.w, 16, 64);
    t.x += __shfl_xor(t.x, 32, 64); t.y += __shfl_xor(t.y, 32, 64);
    t.z += __shfl_xor(t.z, 32, 64); t.w += __shfl_xor(t.w, 32, 64);
    if (e4 == 0) {
        float dn = dinv[node];
        float4 b = ((const float4*)bias)[f4];
        float4 r;
        r.x = fmaf(t.x, dn, b.x); r.y = fmaf(t.y, dn, b.y);
        r.z = fmaf(t.z, dn, b.z); r.w = fmaf(t.w, dn, b.w);
        r.x = r.x > 0.f ? r.x : 0.f; r.y = r.y > 0.f ? r.y : 0.f;
        r.z = r.z > 0.f ? r.z : 0.f; r.w = r.w > 0.f ? r.w : 0.f;
        ((float4*)out)[(size_t)node * 16 + f4] = r;
    }
}

// ------- normlin: GraphNorm(64) single-pass stats + linear 64x64 + dinv -----------
__global__ __launch_bounds__(512) void normlin_k(const float* __restrict__ A,
    const int* __restrict__ gstart, const float* __restrict__ gw,
    const float* __restrict__ gb, const float* __restrict__ ga,
    const float* __restrict__ W, const float* __restrict__ dinv,
    float* __restrict__ out) {
    __shared__ float sW[64 * 64];
    __shared__ float red[512], red2[512];
    __shared__ float sam[64], ssc[64];
    __shared__ float srow[8 * 64];
    int tid = threadIdx.x, lane = tid & 63, wid = tid >> 6;
    int g = blockIdx.x;
    int s = gstart[g], e = gstart[g + 1], cnt = e - s;
    float cntf = (float)(cnt > 1 ? cnt : 1);
    for (int i = tid; i < 64 * 64; i += 512) sW[i] = W[i];
    float sum = 0.f, sq = 0.f;
    for (int i = s + wid; i < e; i += 8) {
        float v = A[(size_t)i * 64 + lane];
        sum += v;
        sq = fmaf(v, v, sq);
    }
    red[tid] = sum; red2[tid] = sq;
    __syncthreads();
    for (int st = 4; st > 0; st >>= 1) {
        if (wid < st) { red[tid] += red[tid + st * 64]; red2[tid] += red2[tid + st * 64]; }
        __syncthreads();
    }
    if (tid < 64) {
        float m = red[tid] / cntf, q = red2[tid] / cntf;
        float am = ga[tid] * m;
        float var = q - 2.f * am * m + am * am;
        sam[tid] = am;
        ssc[tid] = gw[tid] * rsqrtf(var + GN_EPS);
    }
    __syncthreads();
    float am = sam[lane], sc = ssc[lane], bb = gb[lane];
    for (int i = s + wid; i < e; i += 8) {
        float nv = (A[(size_t)i * 64 + lane] - am) * sc + bb;
        srow[wid * 64 + lane] = nv;  // wave-synchronous: write then read within one wave
        float acc = 0.f;
#pragma unroll
        for (int k = 0; k < 64; k++) acc = fmaf(srow[wid * 64 + k], sW[k * 64 + lane], acc);
        out[(size_t)i * 64 + lane] = acc * dinv[i];
    }
}

// ---------------- layer0: GraphNorm(16) + linear 16->64 (block per graph) ---------
__device__ __forceinline__ void l0_body(float* rows, int cnt, int s,
    const float* __restrict__ x, const float* __restrict__ gw,
    const float* __restrict__ gb, const float* __restrict__ ga,
    const float* sW, const float* __restrict__ dinv, float* __restrict__ hs_out,
    float* red, float* red2, float* sstat, float* sscale, int tid) {
    int f = tid & 15, r = tid >> 4;
    int lane = tid & 63, wid = tid >> 6;
    float cntf = (float)(cnt > 1 ? cnt : 1);
    float sum = 0.f, sq = 0.f;
    for (int i = r; i < cnt; i += 32) {
        float v = x[(size_t)(s + i) * 16 + f];
        rows[i * 16 + f] = v;
        sum += v;
        sq = fmaf(v, v, sq);
    }
    red[tid] = sum; red2[tid] = sq;
    __syncthreads();
    for (int st = 16; st > 0; st >>= 1) {
        if (r < st) { red[tid] += red[tid + st * 16]; red2[tid] += red2[tid + st * 16]; }
        __syncthreads();
    }
    if (tid < 16) {
        float m = red[tid] / cntf, q = red2[tid] / cntf;
        float am = ga[tid] * m;
        sstat[tid] = am;
        sscale[tid] = gw[tid] * rsqrtf(q - 2.f * am * m + am * am + GN_EPS);
    }
    __syncthreads();
    float am = sstat[f], sc = sscale[f], bb = gb[f];
    for (int i = r; i < cnt; i += 32) rows[i * 16 + f] = (rows[i * 16 + f] - am) * sc + bb;
    __syncthreads();
    for (int i = wid; i < cnt; i += 8) {
        float acc = 0.f;
#pragma unroll
        for (int k = 0; k < 16; k++) acc = fmaf(rows[i * 16 + k], sW[k * 64 + lane], acc);
        hs_out[(size_t)(s + i) * 64 + lane] = acc * dinv[s + i];
    }
}

__global__ __launch_bounds__(512) void layer0_k(const float* __restrict__ x,
    const int* __restrict__ gstart, const float* __restrict__ gw,
    const float* __restrict__ gb, const float* __restrict__ ga,
    const float* __restrict__ W, const float* __restrict__ dinv,
    float* __restrict__ hs_out, float* __restrict__ spill16) {
    __shared__ float sRows[CAP * 16];
    __shared__ float sW[16 * 64];
    __shared__ float red[512], red2[512];
    __shared__ float sstat[16], sscale[16];
    int tid = threadIdx.x;
    int g = blockIdx.x;
    int s = gstart[g], e = gstart[g + 1], cnt = e - s;
    for (int i = tid; i < 16 * 64; i += 512) sW[i] = W[i];
    __syncthreads();
    if (cnt <= CAP)
        l0_body(sRows, cnt, s, x, gw, gb, ga, sW, dinv, hs_out, red, red2, sstat, sscale, tid);
    else
        l0_body(spill16 + (size_t)s * 16, cnt, s, x, gw, gb, ga, sW, dinv, hs_out, red, red2, sstat, sscale, tid);
}

// ---------------- Pool + MLP head + softmax: block per graph ----------------
__global__ void pool_head_k(const float* __restrict__ x, const int* __restrict__ gstart,
                            const float* __restrict__ Wd, const float* __restrict__ bd,
                            const float* __restrict__ Wo, const float* __restrict__ bo,
                            float* __restrict__ out) {
    __shared__ float red[256];
    __shared__ float sp[64];
    __shared__ float sh[64];
    __shared__ float sl[2];
    int g = blockIdx.x;
    int s = gstart[g], e = gstart[g + 1];
    int cnt = e - s;
    float cntf = (float)(cnt > 1 ? cnt : 1);
    int tid = threadIdx.x;
    int f = tid & 63, r = tid >> 6;
    float sum = 0.f;
    for (int i = s + r; i < e; i += 4) sum += x[(size_t)i * 64 + f];
    red[tid] = sum;
    __syncthreads();
    for (int st = 2; st > 0; st >>= 1) {
        if (r < st) red[tid] += red[tid + st * 64];
        __syncthreads();
    }
    if (tid < 64) sp[tid] = red[tid] / cntf;
    __syncthreads();
    if (tid < 64) {
        float acc = bd[tid];
        for (int k = 0; k < 64; k++) acc = fmaf(sp[k], Wd[k * 64 + tid], acc);
        sh[tid] = acc > 0.f ? acc : 0.f;
    }
    __syncthreads();
    if (tid < 2) {
        float l = bo[tid];
        for (int k = 0; k < 64; k++) l = fmaf(sh[k], Wo[k * 2 + tid], l);
        sl[tid] = l;
    }
    __syncthreads();
    if (tid < 2) {
        float m = fmaxf(sl[0], sl[1]);
        float e0 = expf(sl[0] - m), e1 = expf(sl[1] - m);
        out[g * 2 + tid] = (tid == 0 ? e0 : e1) / (e0 + e1);
    }
}

extern "C" void kernel_launch(void* const* d_in, const int* in_sizes, int n_in,
                              void* d_out, int out_size, void* d_ws, size_t ws_size,
                              hipStream_t stream) {
    const float* x    = (const float*)d_in[0];
    const int* ei     = (const int*)d_in[1];
    const int* batch  = (const int*)d_in[2];
    const float* gn0w = (const float*)d_in[3];
    const float* gn0b = (const float*)d_in[4];
    const float* gn0a = (const float*)d_in[5];
    const float* W1   = (const float*)d_in[6];
    const float* b1   = (const float*)d_in[7];
    const float* gn1w = (const float*)d_in[8];
    const float* gn1b = (const float*)d_in[9];
    const float* gn1a = (const float*)d_in[10];
    const float* W2   = (const float*)d_in[11];
    const float* b2   = (const float*)d_in[12];
    const float* gn2w = (const float*)d_in[13];
    const float* gn2b = (const float*)d_in[14];
    const float* gn2a = (const float*)d_in[15];
    const float* W3   = (const float*)d_in[16];
    const float* b3   = (const float*)d_in[17];
    const float* Wd   = (const float*)d_in[18];
    const float* bd   = (const float*)d_in[19];
    const float* Wo   = (const float*)d_in[20];
    const float* bo   = (const float*)d_in[21];

    char* p = (char*)d_ws;
    auto alloc = [&](size_t bytes) -> void* {
        void* r = (void*)p;
        p += (bytes + 255) & ~(size_t)255;
        return r;
    };
    float* A       = (float*)alloc((size_t)NB_NODES * 64 * 4);
    float* B       = (float*)alloc((size_t)NB_NODES * 64 * 4);
    int* rowptr    = (int*)alloc((size_t)(NB_NODES + 1) * 4);
    int* deg_in    = (int*)alloc((size_t)NB_NODES * 4);
    int* rk        = (int*)alloc((size_t)NB_EDGES * 4);
    int* csr_src   = (int*)alloc((size_t)NB_EDGES * 4);
    float* dinv    = (float*)alloc((size_t)NB_NODES * 4);
    int* gstart    = (int*)alloc((size_t)(NB_GRAPHS + 1) * 4);
    int* bsums     = (int*)alloc(128 * 4);
    int* boffs     = (int*)alloc(128 * 4);
    float* spill16 = (float*)alloc((size_t)NB_NODES * 16 * 4);

    hipMemsetAsync(deg_in, 0, NB_NODES * 4, stream);

    gstart_k<<<4, 256, 0, stream>>>(batch, gstart);
    hist_deg_rank_k<<<6250, 256, 0, stream>>>(ei + NB_EDGES, deg_in, rk);
    node_deg_k<<<391, 256, 0, stream>>>(deg_in, dinv);
    scanA_k<<<98, 256, 0, stream>>>(deg_in, bsums);
    scanB_k<<<1, 128, 0, stream>>>(bsums, boffs);
    scanC_k<<<98, 256, 0, stream>>>(deg_in, boffs, rowptr);
    csr_fill_k<<<6250, 256, 0, stream>>>(ei, rowptr, rk, csr_src);

    layer0_k<<<NB_GRAPHS, 512, 0, stream>>>(x, gstart, gn0w, gn0b, gn0a, W1, dinv, B, spill16);
    aggregate4_k<<<25000, 256, 0, stream>>>(B, rowptr, csr_src, dinv, b1, A);
    normlin_k<<<NB_GRAPHS, 512, 0, stream>>>(A, gstart, gn1w, gn1b, gn1a, W2, dinv, B);
    aggregate4_k<<<25000, 256, 0, stream>>>(B, rowptr, csr_src, dinv, b2, A);
    normlin_k<<<NB_GRAPHS, 512, 0, stream>>>(A, gstart, gn2w, gn2b, gn2a, W3, dinv, B);
    aggregate4_k<<<25000, 256, 0, stream>>>(B, rowptr, csr_src, dinv, b3, A);
    pool_head_k<<<NB_GRAPHS, 256, 0, stream>>>(A, gstart, Wd, bd, Wo, bo, (float*)d_out);
}

// Round 5
// 426.198 us; speedup vs baseline: 2.3087x; 1.1278x over previous
//
#include <hip/hip_runtime.h>
#include <hip/hip_fp16.h>
#include <math.h>

#define NB_NODES 100000
#define NB_EDGES 1600000
#define NB_GRAPHS 1000
#define CAP 232
constexpr float GN_EPS = 1e-5f;

// ---------------- gstart: binary search on sorted batch ----------------
__global__ void gstart_k(const int* __restrict__ batch, int* __restrict__ gstart) {
    int g = blockIdx.x * 256 + threadIdx.x;
    if (g <= NB_GRAPHS) {
        int lo = 0, hi = NB_NODES;
        while (lo < hi) {
            int mid = (lo + hi) >> 1;
            if (batch[mid] < g) lo = mid + 1; else hi = mid;
        }
        gstart[g] = lo;
    }
}

// ---------------- degree histogram + per-edge rank (ILP x4) ----------------
__global__ void hist_deg_rank_k(const int* __restrict__ dst, int* __restrict__ deg_in,
                                int* __restrict__ rk) {
    int base = blockIdx.x * 1024 + threadIdx.x;
#pragma unroll
    for (int t = 0; t < 4; t++) {
        int e = base + t * 256;
        if (e < NB_EDGES) rk[e] = atomicAdd(&deg_in[dst[e]], 1);
    }
}

__global__ void node_deg_k(const int* __restrict__ deg_in, float* __restrict__ dinv) {
    int i = blockIdx.x * 256 + threadIdx.x;
    if (i < NB_NODES) dinv[i] = rsqrtf((float)(deg_in[i] + 1));
}

// ---------------- rowptr scans ----------------
__global__ void scanA_k(const int* __restrict__ deg_in, int* __restrict__ bsums) {
    __shared__ int red[256];
    int tid = threadIdx.x;
    int base = blockIdx.x * 1024 + tid * 4;
    int s = 0;
#pragma unroll
    for (int i = 0; i < 4; i++) s += (base + i < NB_NODES) ? deg_in[base + i] : 0;
    red[tid] = s;
    __syncthreads();
    for (int st = 128; st > 0; st >>= 1) {
        if (tid < st) red[tid] += red[tid + st];
        __syncthreads();
    }
    if (tid == 0) bsums[blockIdx.x] = red[0];
}

__global__ void scanB_k(const int* __restrict__ bsums, int* __restrict__ boffs) {
    __shared__ int s[128];
    int tid = threadIdx.x;
    int own = (tid < 98) ? bsums[tid] : 0;
    s[tid] = own;
    __syncthreads();
    for (int off = 1; off < 128; off <<= 1) {
        int t = (tid >= off) ? s[tid - off] : 0;
        __syncthreads();
        s[tid] += t;
        __syncthreads();
    }
    if (tid < 98) boffs[tid] = s[tid] - own;
}

__global__ void scanC_k(const int* __restrict__ deg_in, const int* __restrict__ boffs,
                        int* __restrict__ rowptr) {
    __shared__ int s[256];
    int tid = threadIdx.x;
    int base = blockIdx.x * 1024 + tid * 4;
    int v[4];
    int tsum = 0;
#pragma unroll
    for (int i = 0; i < 4; i++) {
        v[i] = (base + i < NB_NODES) ? deg_in[base + i] : 0;
        tsum += v[i];
    }
    s[tid] = tsum;
    __syncthreads();
    for (int off = 1; off < 256; off <<= 1) {
        int t = (tid >= off) ? s[tid - off] : 0;
        __syncthreads();
        s[tid] += t;
        __syncthreads();
    }
    int run = boffs[blockIdx.x] + s[tid] - tsum;
#pragma unroll
    for (int i = 0; i < 4; i++) {
        if (base + i < NB_NODES) rowptr[base + i] = run;
        run += v[i];
    }
    if (blockIdx.x == 0 && tid == 0) rowptr[NB_NODES] = NB_EDGES;
}

__global__ void csr_fill_k(const int* __restrict__ ei, const int* __restrict__ rowptr,
                           const int* __restrict__ rk, int* __restrict__ csr_src) {
    int base = blockIdx.x * 512 + threadIdx.x;
#pragma unroll
    for (int t = 0; t < 2; t++) {
        int e = base + t * 256;
        if (e < NB_EDGES) {
            int sidx = ei[e];
            int d = ei[NB_EDGES + e];
            csr_src[rowptr[d] + rk[e]] = sidx;
        }
    }
}

// ---------------- fp16 helpers ----------------
union HU {
    uint4 u;
    __half2 h[4];
};

__device__ __forceinline__ void acc8(float* a, uint4 v) {
    HU x; x.u = v;
    float2 f0 = __half22float2(x.h[0]);
    float2 f1 = __half22float2(x.h[1]);
    float2 f2 = __half22float2(x.h[2]);
    float2 f3 = __half22float2(x.h[3]);
    a[0] += f0.x; a[1] += f0.y; a[2] += f1.x; a[3] += f1.y;
    a[4] += f2.x; a[5] += f2.y; a[6] += f3.x; a[7] += f3.y;
}

// --------- aggregate: wave per node, 8 lanes x uint4 (8 fp16), 8 edges/instr ------
// hs rows prescaled by dinv[src]. out = relu(dinv[dst]*(self + sum_src) + bias), fp16
__global__ __launch_bounds__(256) void aggregate_h_k(const __half* __restrict__ hs,
    const int* __restrict__ rowptr, const int* __restrict__ csr_src,
    const float* __restrict__ dinv, const float* __restrict__ bias,
    __half* __restrict__ out) {
    const uint4* hsv = (const uint4*)hs;  // row = 8 uint4 (64 fp16)
    int node = blockIdx.x * 4 + (threadIdx.x >> 6);
    int lane = threadIdx.x & 63;
    int f8 = lane & 7;   // 16B chunk: features [f8*8, f8*8+8)
    int e8 = lane >> 3;  // edge slot 0..7
    int s = rowptr[node], e = rowptr[node + 1];
    float a0[8] = {0.f, 0.f, 0.f, 0.f, 0.f, 0.f, 0.f, 0.f};
    float a1[8] = {0.f, 0.f, 0.f, 0.f, 0.f, 0.f, 0.f, 0.f};
    if (e8 == 0) acc8(a0, hsv[(size_t)node * 8 + f8]);  // self term
    int j = s;
    for (; j + 16 <= e; j += 16) {
        int u0 = csr_src[j + e8];
        int u1 = csr_src[j + 8 + e8];
        uint4 v0 = hsv[(size_t)u0 * 8 + f8];
        uint4 v1 = hsv[(size_t)u1 * 8 + f8];
        acc8(a0, v0);
        acc8(a1, v1);
    }
    if (j + 8 <= e) {
        int u = csr_src[j + e8];
        acc8(a0, hsv[(size_t)u * 8 + f8]);
        j += 8;
    }
    if (j + e8 < e) {
        int u = csr_src[j + e8];
        acc8(a1, hsv[(size_t)u * 8 + f8]);
    }
#pragma unroll
    for (int c = 0; c < 8; c++) {
        float t = a0[c] + a1[c];
        t += __shfl_xor(t, 8, 64);
        t += __shfl_xor(t, 16, 64);
        t += __shfl_xor(t, 32, 64);
        a0[c] = t;
    }
    if (e8 == 0) {
        float dn = dinv[node];
        const float4* b4 = (const float4*)bias;
        float4 blo = b4[f8 * 2], bhi = b4[f8 * 2 + 1];
        float r[8];
        r[0] = fmaf(a0[0], dn, blo.x); r[1] = fmaf(a0[1], dn, blo.y);
        r[2] = fmaf(a0[2], dn, blo.z); r[3] = fmaf(a0[3], dn, blo.w);
        r[4] = fmaf(a0[4], dn, bhi.x); r[5] = fmaf(a0[5], dn, bhi.y);
        r[6] = fmaf(a0[6], dn, bhi.z); r[7] = fmaf(a0[7], dn, bhi.w);
#pragma unroll
        for (int c = 0; c < 8; c++) r[c] = r[c] > 0.f ? r[c] : 0.f;
        HU o;
        o.h[0] = __floats2half2_rn(r[0], r[1]);
        o.h[1] = __floats2half2_rn(r[2], r[3]);
        o.h[2] = __floats2half2_rn(r[4], r[5]);
        o.h[3] = __floats2half2_rn(r[6], r[7]);
        ((uint4*)out)[(size_t)node * 8 + f8] = o.u;
    }
}

// ------- normlin: GraphNorm(64) single-pass stats + linear 64x64 + dinv -----------
__global__ __launch_bounds__(512) void normlin_k(const __half* __restrict__ A,
    const int* __restrict__ gstart, const float* __restrict__ gw,
    const float* __restrict__ gb, const float* __restrict__ ga,
    const float* __restrict__ W, const float* __restrict__ dinv,
    __half* __restrict__ out) {
    __shared__ float sW[64 * 64];
    __shared__ float red[512], red2[512];
    __shared__ float sam[64], ssc[64];
    __shared__ float srow[8 * 64];
    int tid = threadIdx.x, lane = tid & 63, wid = tid >> 6;
    int g = blockIdx.x;
    int s = gstart[g], e = gstart[g + 1], cnt = e - s;
    float cntf = (float)(cnt > 1 ? cnt : 1);
    for (int i = tid; i < 64 * 64; i += 512) sW[i] = W[i];
    float sum = 0.f, sq = 0.f;
    for (int i = s + wid; i < e; i += 8) {
        float v = __half2float(A[(size_t)i * 64 + lane]);
        sum += v;
        sq = fmaf(v, v, sq);
    }
    red[tid] = sum; red2[tid] = sq;
    __syncthreads();
    for (int st = 4; st > 0; st >>= 1) {
        if (wid < st) { red[tid] += red[tid + st * 64]; red2[tid] += red2[tid + st * 64]; }
        __syncthreads();
    }
    if (tid < 64) {
        float m = red[tid] / cntf, q = red2[tid] / cntf;
        float am = ga[tid] * m;
        float var = q - 2.f * am * m + am * am;
        sam[tid] = am;
        ssc[tid] = gw[tid] * rsqrtf(var + GN_EPS);
    }
    __syncthreads();
    float am = sam[lane], sc = ssc[lane], bb = gb[lane];
    for (int i = s + wid; i < e; i += 8) {
        float nv = (__half2float(A[(size_t)i * 64 + lane]) - am) * sc + bb;
        srow[wid * 64 + lane] = nv;  // wave-synchronous: write then read within one wave
        float acc = 0.f;
#pragma unroll
        for (int k = 0; k < 64; k++) acc = fmaf(srow[wid * 64 + k], sW[k * 64 + lane], acc);
        out[(size_t)i * 64 + lane] = __float2half(acc * dinv[i]);
    }
}

// ---------------- layer0: GraphNorm(16) + linear 16->64 (block per graph) ---------
__device__ __forceinline__ void l0_body(float* rows, int cnt, int s,
    const float* __restrict__ x, const float* __restrict__ gw,
    const float* __restrict__ gb, const float* __restrict__ ga,
    const float* sW, const float* __restrict__ dinv, __half* __restrict__ hs_out,
    float* red, float* red2, float* sstat, float* sscale, int tid) {
    int f = tid & 15, r = tid >> 4;
    int lane = tid & 63, wid = tid >> 6;
    float cntf = (float)(cnt > 1 ? cnt : 1);
    float sum = 0.f, sq = 0.f;
    for (int i = r; i < cnt; i += 32) {
        float v = x[(size_t)(s + i) * 16 + f];
        rows[i * 16 + f] = v;
        sum += v;
        sq = fmaf(v, v, sq);
    }
    red[tid] = sum; red2[tid] = sq;
    __syncthreads();
    for (int st = 16; st > 0; st >>= 1) {
        if (r < st) { red[tid] += red[tid + st * 16]; red2[tid] += red2[tid + st * 16]; }
        __syncthreads();
    }
    if (tid < 16) {
        float m = red[tid] / cntf, q = red2[tid] / cntf;
        float am = ga[tid] * m;
        sstat[tid] = am;
        sscale[tid] = gw[tid] * rsqrtf(q - 2.f * am * m + am * am + GN_EPS);
    }
    __syncthreads();
    float am = sstat[f], sc = sscale[f], bb = gb[f];
    for (int i = r; i < cnt; i += 32) rows[i * 16 + f] = (rows[i * 16 + f] - am) * sc + bb;
    __syncthreads();
    for (int i = wid; i < cnt; i += 8) {
        float acc = 0.f;
#pragma unroll
        for (int k = 0; k < 16; k++) acc = fmaf(rows[i * 16 + k], sW[k * 64 + lane], acc);
        hs_out[(size_t)(s + i) * 64 + lane] = __float2half(acc * dinv[s + i]);
    }
}

__global__ __launch_bounds__(512) void layer0_k(const float* __restrict__ x,
    const int* __restrict__ gstart, const float* __restrict__ gw,
    const float* __restrict__ gb, const float* __restrict__ ga,
    const float* __restrict__ W, const float* __restrict__ dinv,
    __half* __restrict__ hs_out, float* __restrict__ spill16) {
    __shared__ float sRows[CAP * 16];
    __shared__ float sW[16 * 64];
    __shared__ float red[512], red2[512];
    __shared__ float sstat[16], sscale[16];
    int tid = threadIdx.x;
    int g = blockIdx.x;
    int s = gstart[g], e = gstart[g + 1], cnt = e - s;
    for (int i = tid; i < 16 * 64; i += 512) sW[i] = W[i];
    __syncthreads();
    if (cnt <= CAP)
        l0_body(sRows, cnt, s, x, gw, gb, ga, sW, dinv, hs_out, red, red2, sstat, sscale, tid);
    else
        l0_body(spill16 + (size_t)s * 16, cnt, s, x, gw, gb, ga, sW, dinv, hs_out, red, red2, sstat, sscale, tid);
}

// ---------------- Pool + MLP head + softmax: block per graph ----------------
__global__ void pool_head_k(const __half* __restrict__ x, const int* __restrict__ gstart,
                            const float* __restrict__ Wd, const float* __restrict__ bd,
                            const float* __restrict__ Wo, const float* __restrict__ bo,
                            float* __restrict__ out) {
    __shared__ float red[256];
    __shared__ float sp[64];
    __shared__ float sh[64];
    __shared__ float sl[2];
    int g = blockIdx.x;
    int s = gstart[g], e = gstart[g + 1];
    int cnt = e - s;
    float cntf = (float)(cnt > 1 ? cnt : 1);
    int tid = threadIdx.x;
    int f = tid & 63, r = tid >> 6;
    float sum = 0.f;
    for (int i = s + r; i < e; i += 4) sum += __half2float(x[(size_t)i * 64 + f]);
    red[tid] = sum;
    __syncthreads();
    for (int st = 2; st > 0; st >>= 1) {
        if (r < st) red[tid] += red[tid + st * 64];
        __syncthreads();
    }
    if (tid < 64) sp[tid] = red[tid] / cntf;
    __syncthreads();
    if (tid < 64) {
        float acc = bd[tid];
        for (int k = 0; k < 64; k++) acc = fmaf(sp[k], Wd[k * 64 + tid], acc);
        sh[tid] = acc > 0.f ? acc : 0.f;
    }
    __syncthreads();
    if (tid < 2) {
        float l = bo[tid];
        for (int k = 0; k < 64; k++) l = fmaf(sh[k], Wo[k * 2 + tid], l);
        sl[tid] = l;
    }
    __syncthreads();
    if (tid < 2) {
        float m = fmaxf(sl[0], sl[1]);
        float e0 = expf(sl[0] - m), e1 = expf(sl[1] - m);
        out[g * 2 + tid] = (tid == 0 ? e0 : e1) / (e0 + e1);
    }
}

extern "C" void kernel_launch(void* const* d_in, const int* in_sizes, int n_in,
                              void* d_out, int out_size, void* d_ws, size_t ws_size,
                              hipStream_t stream) {
    const float* x    = (const float*)d_in[0];
    const int* ei     = (const int*)d_in[1];
    const int* batch  = (const int*)d_in[2];
    const float* gn0w = (const float*)d_in[3];
    const float* gn0b = (const float*)d_in[4];
    const float* gn0a = (const float*)d_in[5];
    const float* W1   = (const float*)d_in[6];
    const float* b1   = (const float*)d_in[7];
    const float* gn1w = (const float*)d_in[8];
    const float* gn1b = (const float*)d_in[9];
    const float* gn1a = (const float*)d_in[10];
    const float* W2   = (const float*)d_in[11];
    const float* b2   = (const float*)d_in[12];
    const float* gn2w = (const float*)d_in[13];
    const float* gn2b = (const float*)d_in[14];
    const float* gn2a = (const float*)d_in[15];
    const float* W3   = (const float*)d_in[16];
    const float* b3   = (const float*)d_in[17];
    const float* Wd   = (const float*)d_in[18];
    const float* bd   = (const float*)d_in[19];
    const float* Wo   = (const float*)d_in[20];
    const float* bo   = (const float*)d_in[21];

    char* p = (char*)d_ws;
    auto alloc = [&](size_t bytes) -> void* {
        void* r = (void*)p;
        p += (bytes + 255) & ~(size_t)255;
        return r;
    };
    __half* A      = (__half*)alloc((size_t)NB_NODES * 64 * 2);
    __half* B      = (__half*)alloc((size_t)NB_NODES * 64 * 2);
    int* rowptr    = (int*)alloc((size_t)(NB_NODES + 1) * 4);
    int* deg_in    = (int*)alloc((size_t)NB_NODES * 4);
    int* rk        = (int*)alloc((size_t)NB_EDGES * 4);
    int* csr_src   = (int*)alloc((size_t)NB_EDGES * 4);
    float* dinv    = (float*)alloc((size_t)NB_NODES * 4);
    int* gstart    = (int*)alloc((size_t)(NB_GRAPHS + 1) * 4);
    int* bsums     = (int*)alloc(128 * 4);
    int* boffs     = (int*)alloc(128 * 4);
    float* spill16 = (float*)alloc((size_t)NB_NODES * 16 * 4);

    hipMemsetAsync(deg_in, 0, NB_NODES * 4, stream);

    gstart_k<<<4, 256, 0, stream>>>(batch, gstart);
    hist_deg_rank_k<<<1563, 256, 0, stream>>>(ei + NB_EDGES, deg_in, rk);
    node_deg_k<<<391, 256, 0, stream>>>(deg_in, dinv);
    scanA_k<<<98, 256, 0, stream>>>(deg_in, bsums);
    scanB_k<<<1, 128, 0, stream>>>(bsums, boffs);
    scanC_k<<<98, 256, 0, stream>>>(deg_in, boffs, rowptr);
    csr_fill_k<<<3125, 256, 0, stream>>>(ei, rowptr, rk, csr_src);

    layer0_k<<<NB_GRAPHS, 512, 0, stream>>>(x, gstart, gn0w, gn0b, gn0a, W1, dinv, B, spill16);
    aggregate_h_k<<<25000, 256, 0, stream>>>(B, rowptr, csr_src, dinv, b1, A);
    normlin_k<<<NB_GRAPHS, 512, 0, stream>>>(A, gstart, gn1w, gn1b, gn1a, W2, dinv, B);
    aggregate_h_k<<<25000, 256, 0, stream>>>(B, rowptr, csr_src, dinv, b2, A);
    normlin_k<<<NB_GRAPHS, 512, 0, stream>>>(A, gstart, gn2w, gn2b, gn2a, W3, dinv, B);
    aggregate_h_k<<<25000, 256, 0, stream>>>(B, rowptr, csr_src, dinv, b3, A);
    pool_head_k<<<NB_GRAPHS, 256, 0, stream>>>(A, gstart, Wd, bd, Wo, bo, (float*)d_out);
}